// Round 10
// baseline (107.724 us; speedup 1.0000x reference)
//
#include <hip/hip_runtime.h>
#include <hip/hip_fp16.h>

#define B_      8
#define CIN_    256
#define COUT_   256
#define K_      4
#define H_      128
#define W_      128
#define NPTS_   512
#define HW_     (H_ * W_)

#define NPTS_TOT_   (B_ * NPTS_)                 // 4096
#define PROJ_BYTES_ ((size_t)B_ * HW_ * COUT_ * sizeof(__half))     // 67,108,864
#define WTS_OFF_    PROJ_BYTES_
#define SITES_OFF_  (WTS_OFF_   + (size_t)NPTS_TOT_ * 16 * 4)
#define WS_NEED_    (SITES_OFF_ + (size_t)NPTS_TOT_ * 16 * 4)

#define NBLK_GEMM_  ((B_ * HW_) / 64)            // 2048 pixel tiles of 64

typedef __attribute__((ext_vector_type(8))) short short8v;   // 8 bf16
typedef __attribute__((ext_vector_type(4))) float f32x4;

__device__ __forceinline__ unsigned int bf16pair(float a, float b) {
    unsigned int ua = __float_as_uint(a), ub = __float_as_uint(b);
    ua = (ua + 0x7FFFu + ((ua >> 16) & 1u)) >> 16;             // RNE to bf16
    ub = (ub + 0x7FFFu + ((ub >> 16) & 1u)) >> 16;
    return ua | (ub << 16);
}

union GemmSmem {
    struct {
        float          lt[32][65];     // staged input chunk [c][px], pad 65
        unsigned short A[64 * 40];     // A chunk bf16 [px][40-pad k]
        unsigned short wb[256 * 40];   // Wp chunk bf16 [o][40-pad k]
    } s;
    unsigned short ebuf[64][264];      // epilogue bounce [px][cout-pad]
};

// =====================================================================
// K_A: blocks [0,2048): dense proj GEMM. Tile = 64 px x 256 cout, K=256.
//      proj[px][o] = Wp[o,:] @ x[px,:] + bp[o], stored fp16 HWC.
//      blocks [2048,6144): per-point prep (verbatim r4, proven).
// =====================================================================
__global__ __launch_bounds__(256) void ka_kernel(
    const float* __restrict__ input,   // [B, CIN, H, W]
    const float* __restrict__ ax,      // [B, NPTS]
    const float* __restrict__ ay,
    const float* __restrict__ Wp,      // [COUT, CIN]
    const float* __restrict__ bp,      // [COUT]
    const float* __restrict__ Woff,    // [K, 2, CIN]
    const float* __restrict__ boff,    // [K, 2]
    const float* __restrict__ Ww,      // [K, CIN]
    const float* __restrict__ bw,      // [K]
    __half* __restrict__ proj,         // [B*H*W, COUT] fp16
    float* __restrict__ wts_g,         // [4096][16]
    int*   __restrict__ sites_g)       // [4096][16]
{
    __shared__ GemmSmem sm;
    __shared__ float xs[CIN_];
    __shared__ float dotv[12];

    const int bid = blockIdx.x;
    const int t   = threadIdx.x;

    if (bid < NBLK_GEMM_) {
        // ---------------- dense proj GEMM path ----------------
        const int b   = bid >> 8;                // 256 tiles per batch
        const int pxl = (bid & 255) << 6;        // pixel-in-image base
        const size_t px0 = (size_t)b * HW_ + pxl; // global pixel base

        const int wave = t >> 6;                 // 0..3
        const int lane = t & 63;
        const int mn   = lane & 15;
        const int kb4  = lane >> 4;              // 0..3

        // acc init with bias (row-independent): D row = px, col = cout
        f32x4 acc[4][4];
        #pragma unroll
        for (int nf = 0; nf < 4; ++nf) {
            const float bb = bp[wave * 64 + nf * 16 + mn];
            #pragma unroll
            for (int mf = 0; mf < 4; ++mf) {
                acc[mf][nf][0] = bb; acc[mf][nf][1] = bb;
                acc[mf][nf][2] = bb; acc[mf][nf][3] = bb;
            }
        }

        const int cS = t >> 3;                   // 0..31 staging channel
        const int mS = t & 7;                    // 0..7

        for (int ch = 0; ch < 8; ++ch) {
            // ---- stage input chunk [32c x 64px] -> lt (proven r4 pattern) ----
            const float* __restrict__ src =
                input + ((size_t)(b * CIN_ + ch * 32 + cS)) * HW_ + pxl + mS * 4;
            #pragma unroll
            for (int q = 0; q < 2; ++q) {
                const int px = mS * 4 + q * 32;
                const float4 v = *reinterpret_cast<const float4*>(src + q * 32);
                sm.s.lt[cS][px]     = v.x;
                sm.s.lt[cS][px + 1] = v.y;
                sm.s.lt[cS][px + 2] = v.z;
                sm.s.lt[cS][px + 3] = v.w;
            }
            // ---- stage Wp chunk [256o x 32c] -> wb bf16 (proven r8 pattern) ----
            #pragma unroll
            for (int r = 0; r < 8; ++r) {
                const int idx = r * 256 + t;     // 0..2047
                const int o   = idx >> 3;        // 0..255
                const int q   = idx & 7;
                const float4 v = *reinterpret_cast<const float4*>(
                    Wp + (size_t)o * CIN_ + ch * 32 + q * 4);
                unsigned int* w32 = reinterpret_cast<unsigned int*>(&sm.s.wb[o * 40 + q * 4]);
                w32[0] = bf16pair(v.x, v.y);
                w32[1] = bf16pair(v.z, v.w);
            }
            __syncthreads();

            // ---- transpose-pack lt -> A bf16 [px][c] ----
            {
                const int px  = t & 63;
                const int grp = t >> 6;          // c-octet 0..3
                unsigned int u[4];
                #pragma unroll
                for (int i = 0; i < 4; ++i)
                    u[i] = bf16pair(sm.s.lt[grp * 8 + 2 * i][px],
                                    sm.s.lt[grp * 8 + 2 * i + 1][px]);
                *reinterpret_cast<uint4*>(&sm.s.A[px * 40 + grp * 8]) =
                    make_uint4(u[0], u[1], u[2], u[3]);
            }
            __syncthreads();

            // ---- MFMA: wave owns couts [wave*64, +64) ----
            short8v aF[4];
            #pragma unroll
            for (int mf = 0; mf < 4; ++mf)
                aF[mf] = *reinterpret_cast<const short8v*>(
                    &sm.s.A[(mf * 16 + mn) * 40 + kb4 * 8]);
            #pragma unroll
            for (int nf = 0; nf < 4; ++nf) {
                const short8v bF = *reinterpret_cast<const short8v*>(
                    &sm.s.wb[(wave * 64 + nf * 16 + mn) * 40 + kb4 * 8]);
                #pragma unroll
                for (int mf = 0; mf < 4; ++mf)
                    acc[mf][nf] = __builtin_amdgcn_mfma_f32_16x16x32_bf16(
                        aF[mf], bF, acc[mf][nf], 0, 0, 0);
            }
            __syncthreads();
        }

        // ---- epilogue: acc -> ebuf fp16 -> coalesced global ----
        #pragma unroll
        for (int mf = 0; mf < 4; ++mf) {
            const int row = mf * 16 + kb4 * 4;
            #pragma unroll
            for (int nf = 0; nf < 4; ++nf) {
                const int col = wave * 64 + nf * 16 + mn;
                #pragma unroll
                for (int j = 0; j < 4; ++j)
                    sm.ebuf[row + j][col] = __half_as_ushort(__float2half_rn(acc[mf][nf][j]));
            }
        }
        __syncthreads();

        // FIXED mapping: 32 threads per px row (uint4 = 8 shorts each),
        // px = (t>>5) + r*8 covers exactly 0..63; full 256-short rows.
        {
            const int inner = t & 31;            // uint4 slot within row
            #pragma unroll
            for (int r = 0; r < 8; ++r) {
                const int px = (t >> 5) + r * 8;     // 0..63
                const uint4 v = *reinterpret_cast<const uint4*>(&sm.ebuf[px][inner * 8]);
                *reinterpret_cast<uint4*>(
                    reinterpret_cast<unsigned short*>(proj) + (px0 + px) * COUT_ + inner * 8) = v;
            }
        }
        return;
    }

    // ---------------- prep path: one point per block (verbatim r4) ----------------
    const int pt = bid - NBLK_GEMM_;    // 0..4095
    const int b  = pt >> 9;

    const int ix = (int)truncf(ax[pt]);
    const int iy = (int)truncf(ay[pt]);
    const float* __restrict__ chan = input + (size_t)b * (CIN_ * HW_) + (size_t)t * HW_;

    xs[t] = chan[iy * W_ + ix];
    __syncthreads();

    const int wave = t >> 6;
    const int lane = t & 63;
    #pragma unroll
    for (int r = 0; r < 3; ++r) {
        const int d = wave * 3 + r;
        const float* __restrict__ row = (d < 8) ? (Woff + d * CIN_) : (Ww + (d - 8) * CIN_);
        float s = 0.f;
        #pragma unroll
        for (int q = 0; q < 4; ++q) {
            const int c = lane + q * 64;
            s = fmaf(xs[c], row[c], s);
        }
        #pragma unroll
        for (int off = 32; off > 0; off >>= 1)
            s += __shfl_down(s, off);
        if (lane == 0) dotv[d] = s;
    }
    __syncthreads();

    if (t < 4) {
        const int k = t;
        const float l0 = dotv[8]  + bw[0];
        const float l1 = dotv[9]  + bw[1];
        const float l2 = dotv[10] + bw[2];
        const float l3 = dotv[11] + bw[3];
        const float mx = fmaxf(fmaxf(l0, l1), fmaxf(l2, l3));
        const float e0 = expf(l0 - mx), e1 = expf(l1 - mx);
        const float e2 = expf(l2 - mx), e3 = expf(l3 - mx);
        const float ek = (k == 0) ? e0 : (k == 1) ? e1 : (k == 2) ? e2 : e3;
        const float wk = ek / (e0 + e1 + e2 + e3);

        const float scale = 128.0f / 127.0f;
        const float fx = dotv[2 * k]     + boff[2 * k];
        const float fy = dotv[2 * k + 1] + boff[2 * k + 1];
        const float sxv = ((float)ix + fx) * scale - 0.5f;
        const float syv = ((float)iy + fy) * scale - 0.5f;
        const float x0f = floorf(sxv), y0f = floorf(syv);
        const float wx1 = sxv - x0f, wy1 = syv - y0f;
        const int x0 = (int)x0f, y0 = (int)y0f;
        #pragma unroll
        for (int ci = 0; ci < 4; ++ci) {
            const int xi = x0 + (ci & 1);
            const int yi = y0 + (ci >> 1);
            const bool valid = (xi >= 0) & (xi < W_) & (yi >= 0) & (yi < H_);
            float wc = ((ci & 1) ? wx1 : 1.f - wx1) * ((ci >> 1) ? wy1 : 1.f - wy1) * wk;
            wc = valid ? wc : 0.f;
            const int xc = min(max(xi, 0), W_ - 1);
            const int yc = min(max(yi, 0), H_ - 1);
            const int idx = k * 4 + ci;
            wts_g[pt * 16 + idx]   = wc;
            sites_g[pt * 16 + idx] = ((b * H_ + yc) * W_ + xc) * COUT_;
        }
    }
}

// =====================================================================
// K_C: pure weighted gather of proj rows. 256 blocks x 512 threads,
// 16 points per block, thread = (point, cout-octet).
// out[p][o] = sum_s w_s * proj[site_s][o]   (bias already folded in proj)
// =====================================================================
__global__ __launch_bounds__(512) void kc_kernel(
    const __half* __restrict__ proj,
    const float* __restrict__ wts_g,   // [4096][16]
    const int*   __restrict__ sites_g, // [4096][16]
    float* __restrict__ out)           // [4096, COUT]
{
    __shared__ float swts[16][16];
    __shared__ int   ssites[16][16];

    const int blk = blockIdx.x;            // 0..255
    const int p0g = blk << 4;
    const int tid = threadIdx.x;

    if (tid < 256) {
        swts[tid >> 4][tid & 15]   = wts_g[p0g * 16 + tid];
        ssites[tid >> 4][tid & 15] = sites_g[p0g * 16 + tid];
    }
    __syncthreads();

    const int p   = tid >> 5;              // 0..15
    const int oct = tid & 31;              // 0..31
    const int c0  = oct << 3;

    float a[8] = {0.f, 0.f, 0.f, 0.f, 0.f, 0.f, 0.f, 0.f};
    #pragma unroll
    for (int s = 0; s < 16; ++s) {
        const float w = swts[p][s];
        const uint4 raw = *reinterpret_cast<const uint4*>(proj + (size_t)ssites[p][s] + c0);
        const __half* hv = reinterpret_cast<const __half*>(&raw);
        #pragma unroll
        for (int j = 0; j < 8; ++j)
            a[j] = fmaf(w, __half2float(hv[j]), a[j]);
    }

    float* orow = out + (size_t)(p0g + p) * COUT_ + c0;
    *reinterpret_cast<float4*>(orow)     = make_float4(a[0], a[1], a[2], a[3]);
    *reinterpret_cast<float4*>(orow + 4) = make_float4(a[4], a[5], a[6], a[7]);
}

// =====================================================================
// Fallback (round-1 kernel): used only if ws_size is too small.
// =====================================================================
__global__ __launch_bounds__(256) void ple_point_kernel(
    const float* __restrict__ input, const float* __restrict__ ax,
    const float* __restrict__ ay, const float* __restrict__ Wp,
    const float* __restrict__ bp, const float* __restrict__ Woff,
    const float* __restrict__ boff, const float* __restrict__ Ww,
    const float* __restrict__ bw, float* __restrict__ out)
{
    const int gid = blockIdx.x;
    const int b   = gid >> 9;
    const int tid = threadIdx.x;

    __shared__ float xs[CIN_];
    __shared__ float dotv[12];

    const int ix = (int)truncf(ax[gid]);
    const int iy = (int)truncf(ay[gid]);
    const float* __restrict__ chan = input + (size_t)b * (CIN_ * HW_) + (size_t)tid * HW_;

    xs[tid] = chan[iy * W_ + ix];
    __syncthreads();

    const int wave = tid >> 6;
    const int lane = tid & 63;
    #pragma unroll
    for (int r = 0; r < 3; ++r) {
        const int d = wave * 3 + r;
        const float* __restrict__ row = (d < 8) ? (Woff + d * CIN_) : (Ww + (d - 8) * CIN_);
        float s = 0.f;
        #pragma unroll
        for (int q = 0; q < 4; ++q) s = fmaf(xs[lane + q * 64], row[lane + q * 64], s);
        #pragma unroll
        for (int off = 32; off > 0; off >>= 1) s += __shfl_down(s, off);
        if (lane == 0) dotv[d] = s;
    }
    __syncthreads();

    float lg[K_];
    float mx = -1e30f;
    #pragma unroll
    for (int k = 0; k < K_; ++k) { lg[k] = dotv[8 + k] + bw[k]; mx = fmaxf(mx, lg[k]); }
    float se = 0.f;
    #pragma unroll
    for (int k = 0; k < K_; ++k) { lg[k] = expf(lg[k] - mx); se += lg[k]; }
    const float inv_se = 1.f / se;
    const float scale = 128.0f / 127.0f;

    float xacc = 0.f, wsum = 0.f;
    #pragma unroll
    for (int k = 0; k < K_; ++k) {
        const float wk = lg[k] * inv_se;
        const float fx = dotv[2 * k] + boff[2 * k];
        const float fy = dotv[2 * k + 1] + boff[2 * k + 1];
        const float sxv = ((float)ix + fx) * scale - 0.5f;
        const float syv = ((float)iy + fy) * scale - 0.5f;
        const float x0f = floorf(sxv), y0f = floorf(syv);
        const float wx1 = sxv - x0f, wy1 = syv - y0f;
        const int x0 = (int)x0f, y0 = (int)y0f;
        const int x1 = x0 + 1, y1 = y0 + 1;
        const float w00 = (1.f - wx1) * (1.f - wy1) * wk;
        const float w10 = wx1 * (1.f - wy1) * wk;
        const float w01 = (1.f - wx1) * wy1 * wk;
        const float w11 = wx1 * wy1 * wk;
        const bool vx0 = (x0 >= 0) && (x0 < W_);
        const bool vx1 = (x1 >= 0) && (x1 < W_);
        if (y0 >= 0 && y0 < H_) {
            const float* rowp = chan + y0 * W_;
            if (vx0) { xacc = fmaf(w00, rowp[x0], xacc); wsum += w00; }
            if (vx1) { xacc = fmaf(w10, rowp[x1], xacc); wsum += w10; }
        }
        if (y1 >= 0 && y1 < H_) {
            const float* rowp = chan + y1 * W_;
            if (vx0) { xacc = fmaf(w01, rowp[x0], xacc); wsum += w01; }
            if (vx1) { xacc = fmaf(w11, rowp[x1], xacc); wsum += w11; }
        }
    }

    xs[tid] = xacc;
    __syncthreads();

    const float* __restrict__ wrow = Wp + tid * CIN_;
    float a0 = bp[tid] * wsum, a1 = 0.f, a2 = 0.f, a3 = 0.f;
    #pragma unroll 4
    for (int c = 0; c < CIN_; c += 4) {
        const float4 wvv = *reinterpret_cast<const float4*>(wrow + c);
        a0 = fmaf(wvv.x, xs[c], a0);
        a1 = fmaf(wvv.y, xs[c + 1], a1);
        a2 = fmaf(wvv.z, xs[c + 2], a2);
        a3 = fmaf(wvv.w, xs[c + 3], a3);
    }
    out[(size_t)gid * COUT_ + tid] = (a0 + a1) + (a2 + a3);
}

extern "C" void kernel_launch(void* const* d_in, const int* in_sizes, int n_in,
                              void* d_out, int out_size, void* d_ws, size_t ws_size,
                              hipStream_t stream) {
    const float* input = (const float*)d_in[0];
    const float* ax    = (const float*)d_in[1];
    const float* ay    = (const float*)d_in[2];
    const float* Wp    = (const float*)d_in[3];
    const float* bp    = (const float*)d_in[4];
    const float* Woff  = (const float*)d_in[5];
    const float* boff  = (const float*)d_in[6];
    const float* Ww    = (const float*)d_in[7];
    const float* bw    = (const float*)d_in[8];
    float* out = (float*)d_out;

    if (ws_size >= WS_NEED_) {
        __half* proj    = (__half*)d_ws;
        float*  wts_g   = (float*)((char*)d_ws + WTS_OFF_);
        int*    sites_g = (int*)  ((char*)d_ws + SITES_OFF_);

        ka_kernel<<<dim3(NBLK_GEMM_ + NPTS_TOT_), dim3(256), 0, stream>>>(
            input, ax, ay, Wp, bp, Woff, boff, Ww, bw, proj, wts_g, sites_g);
        kc_kernel<<<dim3(NPTS_TOT_ / 16), dim3(512), 0, stream>>>(
            proj, wts_g, sites_g, out);
    } else {
        ple_point_kernel<<<dim3(B_ * NPTS_), dim3(256), 0, stream>>>(
            input, ax, ay, Wp, bp, Woff, boff, Ww, bw, out);
    }
}

// Round 12
// 66.093 us; speedup vs baseline: 1.6299x; 1.6299x over previous
//
#include <hip/hip_runtime.h>
#include <hip/hip_fp16.h>

#define B_      8
#define CIN_    256
#define COUT_   256
#define K_      4
#define H_      128
#define W_      128
#define NPTS_   512

#define NPTS_TOT_   (B_ * NPTS_)                 // 4096
#define T_BYTES_    ((size_t)B_ * H_ * W_ * CIN_ * sizeof(__half))   // 67,108,864
#define WTS_OFF_    T_BYTES_
#define SITES_OFF_  (WTS_OFF_   + (size_t)NPTS_TOT_ * 16 * 4)
#define WSUM_OFF_   (SITES_OFF_ + (size_t)NPTS_TOT_ * 16 * 4)
#define WS_NEED_    (WSUM_OFF_  + (size_t)NPTS_TOT_ * 4)

typedef __attribute__((ext_vector_type(8))) short short8v;   // 8 bf16 (4 VGPRs)
typedef __attribute__((ext_vector_type(4))) float f32x4;
typedef __attribute__((ext_vector_type(4))) unsigned int uint4n;  // native vec for nontemporal

__device__ __forceinline__ unsigned int bf16pair(float a, float b) {
    unsigned int ua = __float_as_uint(a), ub = __float_as_uint(b);
    ua = (ua + 0x7FFFu + ((ua >> 16) & 1u)) >> 16;             // RNE to bf16
    ub = (ub + 0x7FFFu + ((ub >> 16) & 1u)) >> 16;
    return ua | (ub << 16);
}

// =====================================================================
// K_A (r4-proven structure): blocks [0,8192) transpose CHW fp32 ->
// HWC fp16 (granule-complete writes, NONTEMPORAL); blocks
// [8192,12288) per-point prep.
// =====================================================================
__global__ __launch_bounds__(256) void ka_kernel(
    const float* __restrict__ input,   // [B, CIN, H, W]
    const float* __restrict__ ax,      // [B, NPTS]
    const float* __restrict__ ay,
    const float* __restrict__ Woff,    // [K, 2, CIN]
    const float* __restrict__ boff,    // [K, 2]
    const float* __restrict__ Ww,      // [K, CIN]
    const float* __restrict__ bw,      // [K]
    __half* __restrict__ T,            // [B, H, W, C]
    float* __restrict__ wts_g,         // [4096][16]
    int*   __restrict__ sites_g,       // [4096][16]
    float* __restrict__ wsums_g)       // [4096]
{
    __shared__ float lt[32][129];
    __shared__ float xs[CIN_];
    __shared__ float dotv[12];
    __shared__ float wc16[16];

    const int bid = blockIdx.x;
    const int t   = threadIdx.x;

    if (bid < 8192) {
        const int b   = bid >> 10;
        const int r   = bid & 1023;
        const int h   = r >> 3;
        const int c0  = (r & 7) << 5;

        const int c = t >> 3;
        const int m = t & 7;
        const float* __restrict__ src = input + (((size_t)(b * CIN_ + c0 + c) * H_ + h) * W_);
        #pragma unroll
        for (int q = 0; q < 4; ++q) {
            const int w = m * 4 + q * 32;
            const float4 v = *reinterpret_cast<const float4*>(src + w);
            lt[c][w]     = v.x;
            lt[c][w + 1] = v.y;
            lt[c][w + 2] = v.z;
            lt[c][w + 3] = v.w;
        }
        __syncthreads();

        const int wph = t >> 2;
        const int j0  = (t & 3) << 3;
        #pragma unroll
        for (int g = 0; g < 2; ++g) {
            const int w = wph + (g << 6);
            uint4n words;
            #pragma unroll
            for (int i = 0; i < 4; ++i) {
                __half2 h2 = __floats2half2_rn(lt[j0 + 2 * i][w], lt[j0 + 2 * i + 1][w]);
                words[i] = *reinterpret_cast<unsigned int*>(&h2);
            }
            __half* dst = T + (((size_t)(b * H_ + h) * W_ + w) * CIN_ + c0 + j0);
            __builtin_nontemporal_store(words, reinterpret_cast<uint4n*>(dst));
        }
        return;
    }

    const int pt = bid - 8192;
    const int b  = pt >> 9;

    const int ix = (int)truncf(ax[pt]);
    const int iy = (int)truncf(ay[pt]);
    const float* __restrict__ chan = input + (size_t)b * (CIN_ * H_ * W_) + (size_t)t * (H_ * W_);

    xs[t] = chan[iy * W_ + ix];
    __syncthreads();

    const int wave = t >> 6;
    const int lane = t & 63;
    #pragma unroll
    for (int r = 0; r < 3; ++r) {
        const int d = wave * 3 + r;
        const float* __restrict__ row = (d < 8) ? (Woff + d * CIN_) : (Ww + (d - 8) * CIN_);
        float s = 0.f;
        #pragma unroll
        for (int q = 0; q < 4; ++q) {
            const int c = lane + q * 64;
            s = fmaf(xs[c], row[c], s);
        }
        #pragma unroll
        for (int off = 32; off > 0; off >>= 1)
            s += __shfl_down(s, off);
        if (lane == 0) dotv[d] = s;
    }
    __syncthreads();

    if (t < 4) {
        const int k = t;
        const float l0 = dotv[8]  + bw[0];
        const float l1 = dotv[9]  + bw[1];
        const float l2 = dotv[10] + bw[2];
        const float l3 = dotv[11] + bw[3];
        const float mx = fmaxf(fmaxf(l0, l1), fmaxf(l2, l3));
        const float e0 = expf(l0 - mx), e1 = expf(l1 - mx);
        const float e2 = expf(l2 - mx), e3 = expf(l3 - mx);
        const float ek = (k == 0) ? e0 : (k == 1) ? e1 : (k == 2) ? e2 : e3;
        const float wk = ek / (e0 + e1 + e2 + e3);

        const float scale = 128.0f / 127.0f;
        const float fx = dotv[2 * k]     + boff[2 * k];
        const float fy = dotv[2 * k + 1] + boff[2 * k + 1];
        const float sxv = ((float)ix + fx) * scale - 0.5f;
        const float syv = ((float)iy + fy) * scale - 0.5f;
        const float x0f = floorf(sxv), y0f = floorf(syv);
        const float wx1 = sxv - x0f, wy1 = syv - y0f;
        const int x0 = (int)x0f, y0 = (int)y0f;
        #pragma unroll
        for (int ci = 0; ci < 4; ++ci) {
            const int xi = x0 + (ci & 1);
            const int yi = y0 + (ci >> 1);
            const bool valid = (xi >= 0) & (xi < W_) & (yi >= 0) & (yi < H_);
            float wc = ((ci & 1) ? wx1 : 1.f - wx1) * ((ci >> 1) ? wy1 : 1.f - wy1) * wk;
            wc = valid ? wc : 0.f;
            const int xc = min(max(xi, 0), W_ - 1);
            const int yc = min(max(yi, 0), H_ - 1);
            const int idx = k * 4 + ci;
            wc16[idx] = wc;
            wts_g[pt * 16 + idx]   = wc;
            sites_g[pt * 16 + idx] = ((b * H_ + yc) * W_ + xc) * CIN_;
        }
    }
    __syncthreads();
    if (t == 0) {
        float s = 0.f;
        #pragma unroll
        for (int i = 0; i < 16; ++i) s += wc16[i];
        wsums_g[pt] = s;
    }
}

// =====================================================================
// K_B (r8-proven MFMA): 512 blocks x 512 threads. Block = (point-group
// of 16, cout half of 128). Coalesced corner gather from HWC fp16, then
// out[16 x 128] = X[16 x 256] @ Wp_half^T via mfma_f32_16x16x32_bf16.
// =====================================================================
__global__ __launch_bounds__(512) void kb_kernel(
    const __half* __restrict__ T,
    const float* __restrict__ Wp,      // [COUT, CIN] fp32
    const float* __restrict__ bp,      // [COUT]
    const float* __restrict__ wts_g,   // [4096][16]
    const int*   __restrict__ sites_g, // [4096][16]
    const float* __restrict__ wsums_g, // [4096]
    float* __restrict__ out)           // [4096, COUT]
{
    __shared__ float xsh[16][268];
    __shared__ unsigned short wb[128 * 40];
    __shared__ float swts[16][16];
    __shared__ int   ssites[16][16];
    __shared__ float swsum[16];

    const int blk = blockIdx.x;
    const int pg  = blk >> 1;
    const int nh  = blk & 1;
    const int p0g = pg << 4;
    const int tid = threadIdx.x;

    if (tid < 256) {
        swts[tid >> 4][tid & 15]   = wts_g[p0g * 16 + tid];
        ssites[tid >> 4][tid & 15] = sites_g[p0g * 16 + tid];
    } else if (tid < 256 + 16) {
        swsum[tid - 256] = wsums_g[p0g + (tid - 256)];
    }
    __syncthreads();

    {
        const int p   = tid >> 5;
        const int oct = tid & 31;
        const int c0  = oct << 3;
        float a[8] = {0.f, 0.f, 0.f, 0.f, 0.f, 0.f, 0.f, 0.f};
        #pragma unroll
        for (int s = 0; s < 16; ++s) {
            const float w = swts[p][s];
            const uint4 raw = *reinterpret_cast<const uint4*>(T + (size_t)ssites[p][s] + c0);
            const __half* hv = reinterpret_cast<const __half*>(&raw);
            #pragma unroll
            for (int j = 0; j < 8; ++j)
                a[j] = fmaf(w, __half2float(hv[j]), a[j]);
        }
        *reinterpret_cast<float4*>(&xsh[p][c0])     = make_float4(a[0], a[1], a[2], a[3]);
        *reinterpret_cast<float4*>(&xsh[p][c0 + 4]) = make_float4(a[4], a[5], a[6], a[7]);
    }
    __syncthreads();

    const int wave = tid >> 6;
    const int lane = tid & 63;
    const int mn   = lane & 15;
    const int kb4  = lane >> 4;
    const int n0   = nh * 128 + wave * 16;

    const float bpv = bp[n0 + mn];
    f32x4 acc;
    acc[0] = bpv * swsum[kb4 * 4 + 0];
    acc[1] = bpv * swsum[kb4 * 4 + 1];
    acc[2] = bpv * swsum[kb4 * 4 + 2];
    acc[3] = bpv * swsum[kb4 * 4 + 3];

    for (int ch = 0; ch < 8; ++ch) {
        #pragma unroll
        for (int r = 0; r < 2; ++r) {
            const int idx = r * 512 + tid;
            const int o   = idx >> 3;
            const int q   = idx & 7;
            const float4 v = *reinterpret_cast<const float4*>(
                Wp + (size_t)(nh * 128 + o) * CIN_ + ch * 32 + q * 4);
            unsigned int* w32 = reinterpret_cast<unsigned int*>(&wb[o * 40 + q * 4]);
            w32[0] = bf16pair(v.x, v.y);
            w32[1] = bf16pair(v.z, v.w);
        }
        __syncthreads();

        const float* xrow = &xsh[mn][ch * 32 + kb4 * 8];
        const float4 xa = *reinterpret_cast<const float4*>(xrow);
        const float4 xb = *reinterpret_cast<const float4*>(xrow + 4);
        union { unsigned int u[4]; short8v v; } af;
        af.u[0] = bf16pair(xa.x, xa.y);
        af.u[1] = bf16pair(xa.z, xa.w);
        af.u[2] = bf16pair(xb.x, xb.y);
        af.u[3] = bf16pair(xb.z, xb.w);

        const short8v bf = *reinterpret_cast<const short8v*>(&wb[(wave * 16 + mn) * 40 + kb4 * 8]);

        acc = __builtin_amdgcn_mfma_f32_16x16x32_bf16(af.v, bf, acc, 0, 0, 0);
        __syncthreads();
    }

    #pragma unroll
    for (int j = 0; j < 4; ++j)
        __builtin_nontemporal_store(acc[j],
            out + (size_t)(p0g + kb4 * 4 + j) * COUT_ + n0 + mn);
}

// =====================================================================
// Fallback (round-1 kernel): used only if ws_size is too small.
// =====================================================================
__global__ __launch_bounds__(256) void ple_point_kernel(
    const float* __restrict__ input, const float* __restrict__ ax,
    const float* __restrict__ ay, const float* __restrict__ Wp,
    const float* __restrict__ bp, const float* __restrict__ Woff,
    const float* __restrict__ boff, const float* __restrict__ Ww,
    const float* __restrict__ bw, float* __restrict__ out)
{
    const int gid = blockIdx.x;
    const int b   = gid >> 9;
    const int tid = threadIdx.x;

    __shared__ float xs[CIN_];
    __shared__ float dotv[12];

    const int ix = (int)truncf(ax[gid]);
    const int iy = (int)truncf(ay[gid]);
    const float* __restrict__ chan = input + (size_t)b * (CIN_ * H_ * W_) + (size_t)tid * (H_ * W_);

    xs[tid] = chan[iy * W_ + ix];
    __syncthreads();

    const int wave = tid >> 6;
    const int lane = tid & 63;
    #pragma unroll
    for (int r = 0; r < 3; ++r) {
        const int d = wave * 3 + r;
        const float* __restrict__ row = (d < 8) ? (Woff + d * CIN_) : (Ww + (d - 8) * CIN_);
        float s = 0.f;
        #pragma unroll
        for (int q = 0; q < 4; ++q) s = fmaf(xs[lane + q * 64], row[lane + q * 64], s);
        #pragma unroll
        for (int off = 32; off > 0; off >>= 1) s += __shfl_down(s, off);
        if (lane == 0) dotv[d] = s;
    }
    __syncthreads();

    float lg[K_];
    float mx = -1e30f;
    #pragma unroll
    for (int k = 0; k < K_; ++k) { lg[k] = dotv[8 + k] + bw[k]; mx = fmaxf(mx, lg[k]); }
    float se = 0.f;
    #pragma unroll
    for (int k = 0; k < K_; ++k) { lg[k] = expf(lg[k] - mx); se += lg[k]; }
    const float inv_se = 1.f / se;
    const float scale = 128.0f / 127.0f;

    float xacc = 0.f, wsum = 0.f;
    #pragma unroll
    for (int k = 0; k < K_; ++k) {
        const float wk = lg[k] * inv_se;
        const float fx = dotv[2 * k] + boff[2 * k];
        const float fy = dotv[2 * k + 1] + boff[2 * k + 1];
        const float sxv = ((float)ix + fx) * scale - 0.5f;
        const float syv = ((float)iy + fy) * scale - 0.5f;
        const float x0f = floorf(sxv), y0f = floorf(syv);
        const float wx1 = sxv - x0f, wy1 = syv - y0f;
        const int x0 = (int)x0f, y0 = (int)y0f;
        const int x1 = x0 + 1, y1 = y0 + 1;
        const float w00 = (1.f - wx1) * (1.f - wy1) * wk;
        const float w10 = wx1 * (1.f - wy1) * wk;
        const float w01 = (1.f - wx1) * wy1 * wk;
        const float w11 = wx1 * wy1 * wk;
        const bool vx0 = (x0 >= 0) && (x0 < W_);
        const bool vx1 = (x1 >= 0) && (x1 < W_);
        if (y0 >= 0 && y0 < H_) {
            const float* rowp = chan + y0 * W_;
            if (vx0) { xacc = fmaf(w00, rowp[x0], xacc); wsum += w00; }
            if (vx1) { xacc = fmaf(w10, rowp[x1], xacc); wsum += w10; }
        }
        if (y1 >= 0 && y1 < H_) {
            const float* rowp = chan + y1 * W_;
            if (vx0) { xacc = fmaf(w01, rowp[x0], xacc); wsum += w01; }
            if (vx1) { xacc = fmaf(w11, rowp[x1], xacc); wsum += w11; }
        }
    }

    xs[tid] = xacc;
    __syncthreads();

    const float* __restrict__ wrow = Wp + tid * CIN_;
    float a0 = bp[tid] * wsum, a1 = 0.f, a2 = 0.f, a3 = 0.f;
    #pragma unroll 4
    for (int c = 0; c < CIN_; c += 4) {
        const float4 wvv = *reinterpret_cast<const float4*>(wrow + c);
        a0 = fmaf(wvv.x, xs[c], a0);
        a1 = fmaf(wvv.y, xs[c + 1], a1);
        a2 = fmaf(wvv.z, xs[c + 2], a2);
        a3 = fmaf(wvv.w, xs[c + 3], a3);
    }
    out[(size_t)gid * COUT_ + tid] = (a0 + a1) + (a2 + a3);
}

extern "C" void kernel_launch(void* const* d_in, const int* in_sizes, int n_in,
                              void* d_out, int out_size, void* d_ws, size_t ws_size,
                              hipStream_t stream) {
    const float* input = (const float*)d_in[0];
    const float* ax    = (const float*)d_in[1];
    const float* ay    = (const float*)d_in[2];
    const float* Wp    = (const float*)d_in[3];
    const float* bp    = (const float*)d_in[4];
    const float* Woff  = (const float*)d_in[5];
    const float* boff  = (const float*)d_in[6];
    const float* Ww    = (const float*)d_in[7];
    const float* bw    = (const float*)d_in[8];
    float* out = (float*)d_out;

    if (ws_size >= WS_NEED_) {
        __half* T       = (__half*)d_ws;
        float*  wts_g   = (float*)((char*)d_ws + WTS_OFF_);
        int*    sites_g = (int*)  ((char*)d_ws + SITES_OFF_);
        float*  wsums_g = (float*)((char*)d_ws + WSUM_OFF_);

        ka_kernel<<<dim3(8192 + NPTS_TOT_), dim3(256), 0, stream>>>(
            input, ax, ay, Woff, boff, Ww, bw, T, wts_g, sites_g, wsums_g);
        kb_kernel<<<dim3(512), dim3(512), 0, stream>>>(
            T, Wp, bp, wts_g, sites_g, wsums_g, out);
    } else {
        ple_point_kernel<<<dim3(B_ * NPTS_), dim3(256), 0, stream>>>(
            input, ax, ay, Wp, bp, Woff, boff, Ww, bw, out);
    }
}